// Round 9
// baseline (519.362 us; speedup 1.0000x reference)
//
#include <hip/hip_runtime.h>
#include <stdint.h>

#define M_DIM 8192
#define N_DIM 8192
#define K_DIM 1024

typedef int int4v __attribute__((ext_vector_type(4)));

__device__ __forceinline__ int sat8(int v) {
    v = v > 127 ? 127 : v;
    v = v < -128 ? -128 : v;
    return v;
}

// ---- fused pack: blocks [0,8192) pack A; blocks [8192,10240) transpose-pack B ----
__global__ __launch_bounds__(256) void pack_ab_kernel(const int* __restrict__ a,
                                                      const int* __restrict__ b,
                                                      int* __restrict__ outA,
                                                      char* __restrict__ outB) {
    __shared__ char tile[64][68];               // used by B-blocks only
    const int t = threadIdx.x;
    if (blockIdx.x < 8192) {
        // pack a: int32 [M][K] -> int8 [M][K], 4 elems/thread, coalesced
        int i = blockIdx.x * 256 + t;
        int4 v = ((const int4*)a)[i];
        outA[i] = (v.x & 0xff) | ((v.y & 0xff) << 8) |
                  ((v.z & 0xff) << 16) | ((v.w & 0xff) << 24);
        return;
    }
    // pack b: int32 [K][N] -> int8 [N][K] (transpose via LDS tile)
    const int bx = blockIdx.x - 8192;           // 0..2047
    const int n0 = (bx & 127) * 64;
    const int k0 = (bx >> 7) * 64;
    const int tr  = t >> 4;                     // 0..15
    const int tc4 = (t & 15) << 2;              // 0,4,..,60
#pragma unroll
    for (int j = 0; j < 4; ++j) {
        int row = tr + j * 16;                  // k within tile
        int4 v = *(const int4*)&b[(size_t)(k0 + row) * N_DIM + n0 + tc4];
        tile[row][tc4 + 0] = (char)v.x;
        tile[row][tc4 + 1] = (char)v.y;
        tile[row][tc4 + 2] = (char)v.z;
        tile[row][tc4 + 3] = (char)v.w;
    }
    __syncthreads();
#pragma unroll
    for (int j = 0; j < 4; ++j) {
        int n = tr + j * 16;                    // n within tile
        int pk = (tile[tc4 + 0][n] & 0xff) |
                 ((tile[tc4 + 1][n] & 0xff) << 8) |
                 ((tile[tc4 + 2][n] & 0xff) << 16) |
                 ((tile[tc4 + 3][n] & 0xff) << 24);
        *(int*)&outB[(size_t)(n0 + n) * K_DIM + k0 + tc4] = pk;
    }
}

// ---- GEMM: 128x128 tile, LDS-FREE K-loop, register double-buffer, 0 barriers ----
// R8 post-mortem: 7 structural levers (conflicts, counted-vmcnt x2, occupancy,
// MFMA shape, store vectorization, XCD map, 256^2 tile) ALL null; gemm pinned
// at ~135us with no pipe >26% (R7 counters). The one thing never varied was
// the global->LDS->reg operand path: 96KB/K-step through the LDS ports plus
// barrier lockstep around it. K=1024 operands (16MB) are fully L2/L3-resident
// (R7: FETCH=37MB, first-touch only), so this round deletes the LDS from the
// K-loop: each wave gathers its MFMA fragments directly global->reg (lane
// pattern = the i8 16x16x64 layout: row l16, bytes quad*16), double-buffered
// 2 K-steps deep with STATIC reg indexing (rule #20). Unique bytes/CU/K-step
// unchanged (32KB via L1/L2; the 2x wave duplication L1-hits, both sharer
// waves are on the same CU). Deleted: all DMA, all K-loop ds_reads, every
// barrier, every waitcnt drain. Waves run free; compiler's fine-grained vmcnt
// hides ~200-400cy L2 latency under the ~650cy MFMA phase between issue & use.
// Epilogue keeps the per-wave-private LDS transpose (sole LDS user, 0 sync).
__global__ __launch_bounds__(256) void gemm_i8_kernel(const char* __restrict__ A8,
                                                      const char* __restrict__ B8,
                                                      int* __restrict__ C) {
    __shared__ __align__(16) char smem[4 * 8704];   // epilogue transpose only

    const int t    = threadIdx.x;
    // XCD-banded, bm-fast mapping (bijective over 4096 = 8 xcd x 8 band x 64 bn)
    const int xcd  = blockIdx.x & 7;
    const int j    = blockIdx.x >> 3;
    const int bm   = (xcd << 3) | (j & 7);
    const int bn   = j >> 3;
    const int lane = t & 63;
    const int wave = t >> 6;
    const int wm   = wave >> 1;                  // 2x2 wave grid, 64x64 per wave
    const int wn   = wave & 1;
    const int quad = lane >> 4;
    const int l16  = lane & 15;

    // per-lane fragment base: row (..+l16), k-bytes quad*16 (i8 16x16x64 layout)
    const char* aW = A8 + ((size_t)(bm * 128 + wm * 64 + l16) << 10) + quad * 16;
    const char* bW = B8 + ((size_t)(bn * 128 + wn * 64 + l16) << 10) + quad * 16;

    int4v acc[4][4] = {};
    int4v a0[4], b0[4], a1[4], b1[4];            // 2-deep reg double-buffer

    // prologue: K-steps 0 and 1 in flight
#pragma unroll
    for (int mi = 0; mi < 4; ++mi) {
        a0[mi] = *(const int4v*)(aW + mi * 16384);
        b0[mi] = *(const int4v*)(bW + mi * 16384);
    }
#pragma unroll
    for (int mi = 0; mi < 4; ++mi) {
        a1[mi] = *(const int4v*)(aW + mi * 16384 + 64);
        b1[mi] = *(const int4v*)(bW + mi * 16384 + 64);
    }

#pragma unroll
    for (int kt = 0; kt < 16; kt += 2) {
        // compute K-step kt from (a0,b0)
#pragma unroll
        for (int mi = 0; mi < 4; ++mi)
#pragma unroll
            for (int ni = 0; ni < 4; ++ni)
                acc[mi][ni] = __builtin_amdgcn_mfma_i32_16x16x64_i8(
                    a0[mi], b0[ni], acc[mi][ni], 0, 0, 0);
        // prefetch K-step kt+2 into (a0,b0); used one full phase later
        if (kt + 2 < 16) {
#pragma unroll
            for (int mi = 0; mi < 4; ++mi) {
                a0[mi] = *(const int4v*)(aW + mi * 16384 + (kt + 2) * 64);
                b0[mi] = *(const int4v*)(bW + mi * 16384 + (kt + 2) * 64);
            }
        }
        // compute K-step kt+1 from (a1,b1)
#pragma unroll
        for (int mi = 0; mi < 4; ++mi)
#pragma unroll
            for (int ni = 0; ni < 4; ++ni)
                acc[mi][ni] = __builtin_amdgcn_mfma_i32_16x16x64_i8(
                    a1[mi], b1[ni], acc[mi][ni], 0, 0, 0);
        // prefetch K-step kt+3 into (a1,b1)
        if (kt + 3 < 16) {
#pragma unroll
            for (int mi = 0; mi < 4; ++mi) {
                a1[mi] = *(const int4v*)(aW + mi * 16384 + (kt + 3) * 64);
                b1[mi] = *(const int4v*)(bW + mi * 16384 + (kt + 3) * 64);
            }
        }
    }

    // epilogue: acc (C/D layout: col=l16, row=4*quad+reg) -> per-wave LDS
    // transpose region (32 rows x 68-int padded stride) -> dwordx4 stores.
    // Regions are wave-private; no barrier anywhere in this kernel.
    int* lw = (int*)(smem + wave * 8704);        // 32*68 ints = 8704 B
    const int mW = bm * 128 + wm * 64;
    const int nW = bn * 128 + wn * 64;
#pragma unroll
    for (int rnd = 0; rnd < 2; ++rnd) {
#pragma unroll
        for (int mh = 0; mh < 2; ++mh) {         // mi = rnd*2 + mh
            const int mi = rnd * 2 + mh;
#pragma unroll
            for (int ni = 0; ni < 4; ++ni)
#pragma unroll
                for (int r = 0; r < 4; ++r)
                    lw[(mh * 16 + quad * 4 + r) * 68 + ni * 16 + l16] =
                        sat8(acc[mi][ni][r]);
        }
        // same-wave DS ordering: compiler inserts lgkmcnt before dependent reads
#pragma unroll
        for (int rr = 0; rr < 8; ++rr) {
            const int R = rr * 4 + quad;         // local row 0..31
            const int4v v = *(const int4v*)&lw[R * 68 + l16 * 4];
            *(int4v*)&C[(size_t)(mW + rnd * 32 + R) * N_DIM + nW + l16 * 4] = v;
        }
        // round 2 writes ordered after round 1 reads by in-order per-wave DS pipe
    }
}

// ---- fallback (only if ws_size < 16MB): direct int32 GEMM, slow but correct ----
__global__ __launch_bounds__(256) void gemm_naive_kernel(const int* __restrict__ a,
                                                         const int* __restrict__ b,
                                                         int* __restrict__ C) {
    const int col = blockIdx.x * 256 + threadIdx.x;
    const int row = blockIdx.y;
    int acc = 0;
    for (int k = 0; k < K_DIM; ++k)
        acc += a[(size_t)row * K_DIM + k] * b[(size_t)k * N_DIM + col];
    C[(size_t)row * N_DIM + col] = sat8(acc);
}

extern "C" void kernel_launch(void* const* d_in, const int* in_sizes, int n_in,
                              void* d_out, int out_size, void* d_ws, size_t ws_size,
                              hipStream_t stream) {
    const int* a = (const int*)d_in[0];
    const int* b = (const int*)d_in[1];
    // alpha_row (d_in[2]) / alpha_col (d_in[3]) are unused in this variant.
    int* out = (int*)d_out;

    const size_t needed = 2 * (size_t)M_DIM * K_DIM;   // 16 MB packed operands
    if (ws_size < needed) {
        gemm_naive_kernel<<<dim3(N_DIM / 256, M_DIM), 256, 0, stream>>>(a, b, out);
        return;
    }

    char* A8 = (char*)d_ws;                          // 8 MB
    char* B8 = A8 + (size_t)M_DIM * K_DIM;           // 8 MB

    pack_ab_kernel<<<8192 + 2048, 256, 0, stream>>>(a, b, (int*)A8, B8);
    gemm_i8_kernel<<<4096, 256, 0, stream>>>(A8, B8, out);
}

// Round 10
// 366.664 us; speedup vs baseline: 1.4165x; 1.4165x over previous
//
#include <hip/hip_runtime.h>
#include <stdint.h>

#define M_DIM 8192
#define N_DIM 8192
#define K_DIM 1024
#define BK    128

typedef int int4v __attribute__((ext_vector_type(4)));

// ---- async global->LDS, 16B per lane ----
__device__ __forceinline__ void gload16(const char* g, char* l) {
    __builtin_amdgcn_global_load_lds(
        (__attribute__((address_space(1))) void*)(void*)const_cast<char*>(g),
        (__attribute__((address_space(3))) void*)l,
        16, 0, 0);
}

__device__ __forceinline__ int sat8(int v) {
    v = v > 127 ? 127 : v;
    v = v < -128 ? -128 : v;
    return v;
}

// ---- fused pack into TILE-MAJOR layout, T2 swizzle baked at store time ----
// Layout: [blk128][K64-slice(16)][row(128)][64B], 128KB per 128-row block.
// Stored 16B-chunk sc of (row, slice) holds logical chunk sc^((row>>1)&3).
// => GEMM staging reads are fully linear/contiguous (1KB per wave-instr,
// 8 full 128B lines vs 16 scattered 64B segments in the row-major layout).
__global__ __launch_bounds__(256) void pack_ab_kernel(const int* __restrict__ a,
                                                      const int* __restrict__ b,
                                                      char* __restrict__ outA,
                                                      char* __restrict__ outB) {
    __shared__ char tile[64][68];               // used by B-blocks only
    const int t = threadIdx.x;
    if (blockIdx.x < 8192) {
        // pack a: block bx handles row m=bx (1024 int32 -> 1024 int8)
        const int m   = blockIdx.x;
        const int row = m & 127;
        const int xr  = (row >> 1) & 3;          // baked swizzle constant
        const int4 v  = ((const int4*)a)[m * 256 + t];
        const int pk  = (v.x & 0xff) | ((v.y & 0xff) << 8) |
                        ((v.z & 0xff) << 16) | ((v.w & 0xff) << 24);
        const int k     = t * 4;
        const int slice = k >> 6;                // t>>4
        const int sc    = ((k >> 4) & 3) ^ xr;
        *(int*)&outA[(size_t)(m >> 7) * 131072 + slice * 8192 + row * 64 +
                     sc * 16 + (k & 15)] = pk;
        return;
    }
    // pack b: int32 [K][N] -> int8 tile-major [N-blk][K64][n-row][64B] (transpose)
    const int bx = blockIdx.x - 8192;           // 0..2047
    const int n0 = (bx & 127) * 64;
    const int k0 = (bx >> 7) * 64;
    const int tr  = t >> 4;                     // 0..15
    const int tc4 = (t & 15) << 2;              // 0,4,..,60
#pragma unroll
    for (int j = 0; j < 4; ++j) {
        int row = tr + j * 16;                  // k within tile
        int4 v = *(const int4*)&b[(size_t)(k0 + row) * N_DIM + n0 + tc4];
        tile[row][tc4 + 0] = (char)v.x;
        tile[row][tc4 + 1] = (char)v.y;
        tile[row][tc4 + 2] = (char)v.z;
        tile[row][tc4 + 3] = (char)v.w;
    }
    __syncthreads();
    const int slice = k0 >> 6;
#pragma unroll
    for (int j = 0; j < 4; ++j) {
        int n = tr + j * 16;                    // n within tile
        int pk = (tile[tc4 + 0][n] & 0xff) |
                 ((tile[tc4 + 1][n] & 0xff) << 8) |
                 ((tile[tc4 + 2][n] & 0xff) << 16) |
                 ((tile[tc4 + 3][n] & 0xff) << 24);
        const int ng  = n0 + n;
        const int row = ng & 127;
        const int sc  = (tc4 >> 4) ^ ((row >> 1) & 3);
        *(int*)&outB[(size_t)(ng >> 7) * 131072 + slice * 8192 + row * 64 +
                     sc * 16 + (tc4 & 15)] = pk;
    }
}

// ---- GEMM: 128x128 tile, BK=128, 4 waves (R6 core) + tile-major staging ----
// R9 post-mortem: deleting LDS (direct global->reg gather, 16 scattered
// segments/instr) sank to 249us, MfmaUtil 11% -> the L1/TA request pipe is
// the sensitive resource. The row-major packed layout made even the staging
// loads 16x64B scattered segments per instruction; with the tile-major pack
// (swizzle baked), staging source AND LDS dest are fully linear: 1KB
// contiguous per wave-instr, 8 full 128B lines (2x fewer transactions,
// full-line width). K-loop math, ds_read swizzle, epilogue, grid mapping:
// byte-identical to the 363.1us best (R6).
__global__ __launch_bounds__(256) void gemm_i8_kernel(const char* __restrict__ A8,
                                                      const char* __restrict__ B8,
                                                      int* __restrict__ C) {
    // K-loop view: As = smem[0:16K), Bs = smem[16K:32K)  (2 x [K64][row][64B])
    // epilogue view: 4 waves x 32x68-int regions = 34816 B
    __shared__ __align__(16) char smem[4 * 8704];
    char* As = smem;
    char* Bs = smem + 16384;

    const int t    = threadIdx.x;
    // XCD-banded, bm-fast mapping (bijective over 4096 = 8 xcd x 8 band x 64 bn)
    const int xcd  = blockIdx.x & 7;
    const int j    = blockIdx.x >> 3;
    const int bm   = (xcd << 3) | (j & 7);
    const int bn   = j >> 3;
    const int lane = t & 63;
    const int wave = t >> 6;
    const int wm   = wave >> 1;                  // 2x2 wave grid, 64x64 per wave
    const int wn   = wave & 1;
    const int quad = lane >> 4;
    const int l16  = lane & 15;

    const char* aT = A8 + (size_t)bm * 131072;   // tile-major block base
    const char* bT = B8 + (size_t)bn * 131072;

    // swizzled read chunk byte offset (per-lane constant; stored chunk sc
    // holds logical chunk sc^((row>>1)&3), frag rows are multiples of 16)
    const int laneByte = ((quad ^ ((l16 >> 1) & 3)) << 4);

    int4v acc[4][4] = {};

    for (int kt = 0; kt < K_DIM / BK; ++kt) {
        const size_t kBase = (size_t)kt * 16384; // two 8KB K64-slices
#pragma unroll
        for (int s = 0; s < 4; ++s) {
            const int f = s * 4096 + t * 16;     // linear in BOTH spaces
            gload16(aT + kBase + f, As + f);
            gload16(bT + kBase + f, Bs + f);
        }
        __syncthreads();   // drains vmcnt -> staged data visible

#pragma unroll
        for (int h = 0; h < 2; ++h) {            // two K64-slices per stage
            int4v af[4], bf[4];
#pragma unroll
            for (int mi = 0; mi < 4; ++mi)
                af[mi] = *(const int4v*)
                    &As[h * 8192 + (wm * 64 + mi * 16 + l16) * 64 + laneByte];
#pragma unroll
            for (int ni = 0; ni < 4; ++ni)
                bf[ni] = *(const int4v*)
                    &Bs[h * 8192 + (wn * 64 + ni * 16 + l16) * 64 + laneByte];

#pragma unroll
            for (int mi = 0; mi < 4; ++mi)
#pragma unroll
                for (int ni = 0; ni < 4; ++ni)
                    acc[mi][ni] = __builtin_amdgcn_mfma_i32_16x16x64_i8(
                        af[mi], bf[ni], acc[mi][ni], 0, 0, 0);
        }

        __syncthreads();   // LDS reads done before next stage overwrites
    }
    // after final barrier no wave touches As/Bs for the K-loop again; LDS is
    // repurposed per-wave (disjoint regions, no further barrier needed).

    // epilogue: acc (C/D layout: col=l16, row=4*quad+reg) -> per-wave LDS
    // transpose region (32 rows x 68-int padded stride) -> dwordx4 stores.
    int* lw = (int*)(smem + wave * 8704);        // 32*68 ints = 8704 B
    const int mW = bm * 128 + wm * 64;
    const int nW = bn * 128 + wn * 64;
#pragma unroll
    for (int rnd = 0; rnd < 2; ++rnd) {
#pragma unroll
        for (int mh = 0; mh < 2; ++mh) {         // mi = rnd*2 + mh
            const int mi = rnd * 2 + mh;
#pragma unroll
            for (int ni = 0; ni < 4; ++ni)
#pragma unroll
                for (int r = 0; r < 4; ++r)
                    lw[(mh * 16 + quad * 4 + r) * 68 + ni * 16 + l16] =
                        sat8(acc[mi][ni][r]);
        }
        // same-wave DS ordering: compiler inserts lgkmcnt before dependent reads
#pragma unroll
        for (int rr = 0; rr < 8; ++rr) {
            const int R = rr * 4 + quad;         // local row 0..31
            const int4v v = *(const int4v*)&lw[R * 68 + l16 * 4];
            *(int4v*)&C[(size_t)(mW + rnd * 32 + R) * N_DIM + nW + l16 * 4] = v;
        }
        // round 2 writes ordered after round 1 reads by in-order per-wave DS pipe
    }
}

// ---- fallback (only if ws_size < 16MB): direct int32 GEMM, slow but correct ----
__global__ __launch_bounds__(256) void gemm_naive_kernel(const int* __restrict__ a,
                                                         const int* __restrict__ b,
                                                         int* __restrict__ C) {
    const int col = blockIdx.x * 256 + threadIdx.x;
    const int row = blockIdx.y;
    int acc = 0;
    for (int k = 0; k < K_DIM; ++k)
        acc += a[(size_t)row * K_DIM + k] * b[(size_t)k * N_DIM + col];
    C[(size_t)row * N_DIM + col] = sat8(acc);
}

extern "C" void kernel_launch(void* const* d_in, const int* in_sizes, int n_in,
                              void* d_out, int out_size, void* d_ws, size_t ws_size,
                              hipStream_t stream) {
    const int* a = (const int*)d_in[0];
    const int* b = (const int*)d_in[1];
    // alpha_row (d_in[2]) / alpha_col (d_in[3]) are unused in this variant.
    int* out = (int*)d_out;

    const size_t needed = 2 * (size_t)M_DIM * K_DIM;   // 16 MB packed operands
    if (ws_size < needed) {
        gemm_naive_kernel<<<dim3(N_DIM / 256, M_DIM), 256, 0, stream>>>(a, b, out);
        return;
    }

    char* A8 = (char*)d_ws;                          // 8 MB
    char* B8 = A8 + (size_t)M_DIM * K_DIM;           // 8 MB

    pack_ab_kernel<<<8192 + 2048, 256, 0, stream>>>(a, b, A8, B8);
    gemm_i8_kernel<<<4096, 256, 0, stream>>>(A8, B8, out);
}